// Round 12
// baseline (192.904 us; speedup 1.0000x reference)
//
#include <hip/hip_runtime.h>
#include <math.h>

#pragma clang fp contract(off)

#define NXP   8192
#define GROUP 4      // 4 lanes per x-point = numpy's 4 complex pairwise accumulators
#define CPN   32     // 32 sequential terms per accumulator (stride 4)
#define NITER 40

// Identity inline-asm: pins a value into a VGPR and makes it opaque to the
// compiler so it CANNOT rematerialize (re-load) it inside the loop.
// Bitwise-neutral.
#define KEEP(v) asm("" : "+v"(v))

// Quad-lane butterfly add via DPP quad_perm (VALU pipe, no LDS).
template <int CTRL>
__device__ __forceinline__ float qxor_add(float v) {
    int s = __builtin_amdgcn_update_dpp(0, __float_as_int(v), CTRL, 0xF, 0xF, true);
    return v + __int_as_float(s);
}
#define RED4(v) do {                         \
    v = qxor_add<0xB1>(v);  /* quad xor 1 */ \
    v = qxor_add<0x4E>(v);  /* quad xor 2 */ \
} while (0)

// Correctly-rounded f32 divide for NORMAL-range operands (Markstein):
// bit-identical to IEEE a/b in our operand range; no s_setreg mode toggles.
__device__ __forceinline__ float div_ieee(float a, float b) {
    float r = __builtin_amdgcn_rcpf(b);
    float e = __builtin_fmaf(-b, r, 1.0f);
    r = __builtin_fmaf(e, r, r);
    e = __builtin_fmaf(-b, r, 1.0f);
    r = __builtin_fmaf(e, r, r);          // r ~ 1/b to ~0.5 ulp
    float q = a * r;
    float res = __builtin_fmaf(-b, q, a); // exact residual
    return __builtin_fmaf(res, r, q);     // correctly-rounded quotient
}

// numpy npy_cdivf (Smith), numerator (nr + 0i), branchless, nr > 0.
__device__ __forceinline__ void cdiv_nr(float nr, float dr, float di,
                                        float& qr, float& qi) {
    bool sw  = fabsf(di) > fabsf(dr);     // false -> numpy branch A (|dr|>=|di|)
    float u  = sw ? di : dr;
    float v  = sw ? dr : di;
    float rat = div_ieee(v, u);
    float w   = v * rat;
    float scl = div_ieee(1.0f, u + w);
    float t1  = nr * rat;
    float qrn = sw ? t1 : nr;             // A: nr        B: nr*rat
    float qin = sw ? nr : t1;             // A: nr*rat    B: nr
    qr = qrn * scl;
    qi = -qin * scl;                      // neg folds into mul modifier; ±0-safe
}

__global__ __launch_bounds__(128, 1) void wesper_kernel(
    const float* __restrict__ x,
    const float* __restrict__ d,
    const float* __restrict__ wd,
    const float* __restrict__ tau,
    const float* __restrict__ wt,
    float* __restrict__ out)
{
#pragma clang fp contract(off)
    const int tid = threadIdx.x;
    const int L   = tid & (GROUP - 1);
    const int gid = blockIdx.x * (blockDim.x / GROUP) + (tid >> 2);

    // numpy pairwise_sum_CFLOAT, n=128 complex <= blocksize: no recursion;
    // 4 complex accumulators, acc L sums elements L, L+4, ..., L+124 sequentially.
    // KEEP() pins the loop-resident coefficients in VGPRs (R10 post-mortem:
    // without it the allocator re-loads them from global EVERY iteration).
    float tauC[CPN], wttC[CPN], cdC[CPN], wddC[CPN];
    #pragma unroll
    for (int t = 0; t < CPN; ++t) {
        int k = L + (t << 2);
        float tk = tau[k], wk = wt[k];
        tauC[t] = tk;
        wttC[t] = wk * tk;      // wt_tau (one f32 round)
        float dj = d[k];
        cdC[t]  = 0.5f * dj;    // c*d (exact halving)
        wddC[t] = wd[k] * dj;   // wd_d (one f32 round)
        KEEP(tauC[t]); KEEP(wttC[t]); KEEP(cdC[t]); KEEP(wddC[t]);
    }
    const float xv = x[gid];

    // m0 = np.sum(wd*d): real pairwise, 8 accumulators stride 8,
    // combine ((r0+r1)+(r2+r3)) + ((r4+r5)+(r6+r7)).
    float rA = 0.0f, rB = 0.0f;
    #pragma unroll
    for (int t = 0; t < 16; ++t) {
        int kA = L + (t << 3);
        int kB = kA + 4;
        float vA = wd[kA] * d[kA];
        float vB = wd[kB] * d[kB];
        rA = (t == 0) ? vA : (rA + vA);
        rB = (t == 0) ? vB : (rB + vB);
    }
    RED4(rA);
    RED4(rB);
    float m0 = rA + rB;

    float mr = m0, mi = -1.0f;

    for (int it = 0; it < NITER; ++it) {
        // S = sum_k wt_tau_k / (tau_k*m - x)
        float sre = 0.0f, sim = 0.0f;
        #pragma unroll
        for (int t = 0; t < CPN; ++t) {
            float dr = tauC[t] * mr - xv;   // two f32 rounds, no fma
            float di = tauC[t] * mi;
            float qr, qi;
            cdiv_nr(wttC[t], dr, di, qr, qi);
            sre = (t == 0) ? qr : (sre + qr);
            sim = (t == 0) ? qi : (sim + qi);
        }
        RED4(sre);
        RED4(sim);

        // F = sum_j wd_d_j / (1 + (c*d_j)*S)
        float fre = 0.0f, fim = 0.0f;
        #pragma unroll
        for (int t = 0; t < CPN; ++t) {
            float er = 1.0f + cdC[t] * sre;
            float ei = cdC[t] * sim;
            float qr, qi;
            cdiv_nr(wddC[t], er, ei, qr, qi);
            fre = (t == 0) ? qr : (fre + qr);
            fim = (t == 0) ? qi : (fim + qi);
        }
        RED4(fre);
        RED4(fim);

        float mnre = fre;
        float mnim = fminf(fim, -1e-10f);   // Im < 0 branch clamp
        mr = 0.5f * mr + 0.5f * mnre;       // exact halvings + one add round
        mi = 0.5f * mi + 0.5f * mnim;
    }

    // m(x) = sum_k wt_k / (tau_k*m_tilde - x)
    // wt is deliberately NOT pinned: loaded (from cache) only here, once.
    float ore = 0.0f, oim = 0.0f;
    #pragma unroll
    for (int t = 0; t < CPN; ++t) {
        int k = L + (t << 2);
        float dr = tauC[t] * mr - xv;
        float di = tauC[t] * mi;
        float qr, qi;
        cdiv_nr(wt[k], dr, di, qr, qi);
        ore = (t == 0) ? qr : (ore + qr);
        oim = (t == 0) ? qi : (oim + qi);
    }
    RED4(ore);
    RED4(oim);

    if (L == 0) {
        // Layout (verified passing R7-R10): [f | m.real | X.real], 24576 floats.
        out[gid]           = (float)((double)fabsf(oim) / 3.141592653589793);
        out[NXP + gid]     = ore;
        float scl = div_ieee(1.0f, xv);         // Smith with zero-imag denom
        out[2 * NXP + gid] = -mr * scl;         // X.real
    }
}

extern "C" void kernel_launch(void* const* d_in, const int* in_sizes, int n_in,
                              void* d_out, int out_size, void* d_ws, size_t ws_size,
                              hipStream_t stream) {
    const float* x   = (const float*)d_in[0];
    const float* d   = (const float*)d_in[1];
    const float* wd  = (const float*)d_in[2];
    const float* tau = (const float*)d_in[3];
    const float* wt  = (const float*)d_in[4];
    float* out = (float*)d_out;

    // 128 threads/block = 32 points/block -> 256 blocks (1 per CU, 2 waves each).
    const int pts_per_block = 128 / GROUP;
    const int nblocks = NXP / pts_per_block;
    wesper_kernel<<<nblocks, 128, 0, stream>>>(x, d, wd, tau, wt, out);
}